// Round 4
// baseline (86.838 us; speedup 1.0000x reference)
//
#include <hip/hip_runtime.h>

#define BB 192          // B
#define NN 384          // 2B
#define DD 512          // D
#define EPSF 1e-8f
#define MARGINF 0.1f
#define BKT 128         // K-tile staged in LDS
#define PAD 34          // k-major LDS row stride (float2 reads conflict-free)

// ws layout (floats):
// [0, NN)      : ninv[i] = 1/||raw row i|| (written by diagonal gram blocks)
// [NN]         : accum[0] = sum
// [NN+1]       : accum[1] = count
// [NN+2]       : ticket (unsigned)
// [512, ...)   : G[NN*NN] raw gram

__global__ __launch_bounds__(256) void gram_kernel(const float* __restrict__ o1,
                                                   const float* __restrict__ o2,
                                                   float* __restrict__ G,
                                                   float* __restrict__ ninv,
                                                   float* __restrict__ accum,
                                                   unsigned* __restrict__ ticket) {
    int t = threadIdx.x;
    int bi = blockIdx.x, bk = blockIdx.y;
    if (bi == 0 && bk == 0 && t == 0) {
        accum[0] = 0.0f; accum[1] = 0.0f; *ticket = 0u;
    }
    __shared__ float As[BKT][PAD];
    __shared__ float Bs[BKT][PAD];
    int ai0 = bi * 32, ki0 = bk * 32;
    const float4* Asrc = reinterpret_cast<const float4*>(
        (bi < 6) ? o1 + (size_t)ai0 * DD : o2 + (size_t)(ai0 - BB) * DD);
    const float4* Bsrc = reinterpret_cast<const float4*>(
        (bk < 6) ? o1 + (size_t)ki0 * DD : o2 + (size_t)(ki0 - BB) * DD);
    int tx = t & 15, ty = t >> 4;
    float acc00 = 0.f, acc01 = 0.f, acc10 = 0.f, acc11 = 0.f;
    for (int kt = 0; kt < DD / BKT; ++kt) {
        int k04 = kt * (BKT / 4);
        __syncthreads();                  // protect previous iter's reads
        #pragma unroll
        for (int j = 0; j < 4; ++j) {
            int id = j * 256 + t;
            int row = id >> 5, c4 = id & 31;
            float4 va = Asrc[(size_t)row * (DD / 4) + k04 + c4];
            float4 vb = Bsrc[(size_t)row * (DD / 4) + k04 + c4];
            int kk = c4 << 2;
            As[kk][row] = va.x; As[kk + 1][row] = va.y;
            As[kk + 2][row] = va.z; As[kk + 3][row] = va.w;
            Bs[kk][row] = vb.x; Bs[kk + 1][row] = vb.y;
            Bs[kk + 2][row] = vb.z; Bs[kk + 3][row] = vb.w;
        }
        __syncthreads();
        #pragma unroll 8
        for (int kk = 0; kk < BKT; ++kk) {
            float2 a = *reinterpret_cast<const float2*>(&As[kk][ty * 2]);
            float2 b = *reinterpret_cast<const float2*>(&Bs[kk][tx * 2]);
            acc00 += a.x * b.x; acc01 += a.x * b.y;
            acc10 += a.y * b.x; acc11 += a.y * b.y;
        }
    }
    int gi = ai0 + ty * 2, gk = ki0 + tx * 2;
    G[(size_t)gi * NN + gk]           = acc00;
    G[(size_t)gi * NN + gk + 1]       = acc01;
    G[(size_t)(gi + 1) * NN + gk]     = acc10;
    G[(size_t)(gi + 1) * NN + gk + 1] = acc11;
    // diagonal blocks also produce the row inverse norms
    if (bi == bk && tx == ty) {
        ninv[gi]     = 1.0f / fmaxf(sqrtf(acc00), 1e-12f);
        ninv[gi + 1] = 1.0f / fmaxf(sqrtf(acc11), 1e-12f);
    }
}

__global__ void loss_kernel(const float* __restrict__ G,
                            const float* __restrict__ ninv,
                            const float* __restrict__ weight,
                            float* __restrict__ accum,
                            unsigned* __restrict__ ticket,
                            float* __restrict__ out) {
    int i = blockIdx.x;
    int t = threadIdx.x;
    int w = t >> 6, lane = t & 63;
    int ib = (i < BB) ? i : i - BB;
    int p  = (i < BB) ? i + BB : i - BB;
    float ninv_i = ninv[i];
    const float* Gi = G + (size_t)i * NN;

    float cosp = Gi[p] * ninv_i * ninv[p];
    float d2p = fmaxf(0.0f, 2.0f - 2.0f * cosp);
    float dpos = (d2p > 0.0f) ? sqrtf(d2p) : 0.0f;

    float lsum = 0.0f, lcnt = 0.0f;
    for (int k = t; k < NN; k += 256) {
        int kb = (k < BB) ? k : k - BB;
        if (kb == ib) continue;           // same label (k==i or k==p)
        float c = Gi[k] * ninv_i * ninv[k];
        float d2 = fmaxf(0.0f, 2.0f - 2.0f * c);
        float dik = (d2 > 0.0f) ? sqrtf(d2) : 0.0f;
        float tl = dpos - dik + MARGINF;
        if (tl > 0.0f) {
            float v = tl * weight[(size_t)ib * BB + kb];
            lsum += v;
            if (v > EPSF) lcnt += 1.0f;
        }
    }
    for (int off = 32; off >= 1; off >>= 1) {
        lsum += __shfl_xor(lsum, off);
        lcnt += __shfl_xor(lcnt, off);
    }
    __shared__ float ssum[4], scnt[4];
    if (lane == 0) { ssum[w] = lsum; scnt[w] = lcnt; }
    __syncthreads();
    if (t == 0) {
        atomicAdd(&accum[0], ssum[0] + ssum[1] + ssum[2] + ssum[3]);
        atomicAdd(&accum[1], scnt[0] + scnt[1] + scnt[2] + scnt[3]);
        __threadfence();
        unsigned r = atomicAdd(ticket, 1u);
        if (r == NN - 1) {                // last block finalizes
            float s = atomicAdd(&accum[0], 0.0f);   // device-scope read
            float c = atomicAdd(&accum[1], 0.0f);
            out[0] = s / (c + EPSF);
        }
    }
}

extern "C" void kernel_launch(void* const* d_in, const int* in_sizes, int n_in,
                              void* d_out, int out_size, void* d_ws, size_t ws_size,
                              hipStream_t stream) {
    const float* o1 = (const float*)d_in[0];
    const float* o2 = (const float*)d_in[1];
    const float* w  = (const float*)d_in[2];
    float* out = (float*)d_out;

    float* ws_f      = (float*)d_ws;
    float* ninv      = ws_f;
    float* accum     = ws_f + NN;
    unsigned* ticket = (unsigned*)(ws_f + NN + 2);
    float* G         = ws_f + 512;

    gram_kernel<<<dim3(12, 12), 256, 0, stream>>>(o1, o2, G, ninv, accum, ticket);
    loss_kernel<<<NN, 256, 0, stream>>>(G, ninv, w, accum, ticket, out);
}